// Round 12
// baseline (435.713 us; speedup 1.0000x reference)
//
#include <hip/hip_runtime.h>

#define TPB 256  // 4 waves = 2 row-halves x 2 q-halves; block = 64 rows x 128 q

typedef _Float16 f16x8 __attribute__((ext_vector_type(8)));
typedef __fp16 h16x2 __attribute__((ext_vector_type(2)));  // cvt_pkrtz native type
typedef float f32x4 __attribute__((ext_vector_type(4)));

// fp16 weight tiles (16x16x32 B-fragment order), tile(n-1, s, t) of 512 f16:
static constexpr int WT_L0 = 0;        // 8n*2s*8t*512 = 65536
static constexpr int WT_L1 = 65536;    // 8n*4s*8t*512 = 131072 each
static constexpr int WT_L2 = 196608;
static constexpr int WT_L3 = 327680;
static constexpr int WT_END = 458752;          // f16 elements per plane (hi, lo)
static constexpr int F32_BASE = WT_END;        // float offset into ws (2 f16 planes)
static constexpr int MST = 132;                // mT row stride (floats)

// ---------- helpers ----------
__device__ __forceinline__ float fast_tanh2(float x) {  // 2*tanh(x)
  float e = __expf(2.0f * x);
  return fmaf(-4.0f, __builtin_amdgcn_rcpf(e + 1.0f), 2.0f);
}
__device__ __forceinline__ float gelu_exact(float v) {
  return 0.5f * v * (1.0f + erff(v * 0.70710678f));
}

// ---------- fusion kernels (verified R8 layout, unchanged) ----------
// within-tile e = lane*8 + j: q = lane&15 (bits 3..6), g = lane>>4 (bits 7..8)
// p = s*32 + g*8 + j ; qg = t*16 + q ; coef n = n1+1
__global__ void fuse_w_f16(const float* __restrict__ W, const float* __restrict__ tW,
                           _Float16* __restrict__ out_hi, _Float16* __restrict__ out_lo,
                           int P, int total, int sbits) {
  int i = blockIdx.x * 256 + threadIdx.x;
  if (i >= total) return;
  int j = i & 7, q = (i >> 3) & 15, g = (i >> 7) & 3, t = (i >> 9) & 7;
  int s = (i >> 12) & ((1 << sbits) - 1);
  int n1 = i >> (12 + sbits);  // n-1 in 0..7
  int p = s * 32 + g * 8 + j;
  int qg = t * 16 + q;
  float v = tW[(qg * P + p) * 9 + (n1 + 1)] * W[qg * P + p];
  _Float16 hi = (_Float16)v;
  out_hi[i] = hi;
  out_lo[i] = (_Float16)(v - (float)hi);
}
__global__ void fuse_bias(const float* __restrict__ W, const float* __restrict__ tW,
                          float* __restrict__ bias, int P, int Q) {
  int q = blockIdx.x * 64 + threadIdx.x;
  if (q >= Q) return;
  float s = 0.0f;
  for (int p = 0; p < P; ++p) s += tW[(q * P + p) * 9] * W[q * P + p];
  bias[q] = s;
}
__global__ void fuse_w4(const float* __restrict__ W, const float* __restrict__ tW,
                        float* __restrict__ out) {
  int i = blockIdx.x * 128 + threadIdx.x;
  if (i >= 1152) return;
  out[i] = tW[i] * W[i / 9];
}

// ---------- 2x2 layer: wave (wr,wc) computes rows wr*32..+31 x cols wc*64..+63 ----------
// Lane-local recurrence for 2 rt x 8 p-slots; B single-buffered, issued early.
template <int S, bool RES>
__device__ __forceinline__ void layer22(const float* __restrict__ mT,
                                        const _Float16* __restrict__ wt_hi,
                                        const _Float16* __restrict__ wt_lo,
                                        const float* __restrict__ biasL,
                                        f32x4 (&acc)[2][4], int l, int wr, int wc) {
  const int c15 = l & 15, g = l >> 4;
#pragma unroll
  for (int qt = 0; qt < 4; ++qt) {
    float bv = biasL[wc * 64 + qt * 16 + c15];
#pragma unroll
    for (int rtl = 0; rtl < 2; ++rtl)
#pragma unroll
      for (int j = 0; j < 4; ++j) {
        if (RES) acc[rtl][qt][j] += bv; else acc[rtl][qt][j] = bv;
      }
  }
  const _Float16* bh_base = wt_hi + wc * 2048 + l * 8;  // tiles t = wc*4 .. wc*4+3
  const _Float16* bl_base = wt_lo + wc * 2048 + l * 8;
  float mv[2][8], up[2][8], uc[2][8];
#pragma unroll 1
  for (int k = 0; k < 8 * S; ++k) {
    int s = k >> 3, n1 = k & 7;
    // B loads issued first; recurrence+pack (~100 cyc) covers latency
    size_t toff = (size_t)(n1 * S + s) * 4096;
    f16x8 bh[4], bl[4];
#pragma unroll
    for (int qt = 0; qt < 4; ++qt) {
      bh[qt] = *(const f16x8*)(bh_base + toff + qt * 512);
      bl[qt] = *(const f16x8*)(bl_base + toff + qt * 512);
    }
    if (n1 == 0) {
#pragma unroll
      for (int rtl = 0; rtl < 2; ++rtl) {
        const f32x4* mp = (const f32x4*)(mT + (wr * 32 + rtl * 16 + c15) * MST +
                                         s * 32 + g * 8);
        f32x4 a = mp[0], b = mp[1];
#pragma unroll
        for (int i = 0; i < 4; ++i) { mv[rtl][i] = a[i]; mv[rtl][4 + i] = b[i]; }
#pragma unroll
        for (int i = 0; i < 8; ++i) { up[rtl][i] = 1.0f; uc[rtl][i] = mv[rtl][i]; }
      }
    } else {
#pragma unroll
      for (int rtl = 0; rtl < 2; ++rtl)
#pragma unroll
        for (int i = 0; i < 8; ++i) {
          float u = fmaf(mv[rtl][i], uc[rtl][i], -up[rtl][i]);
          up[rtl][i] = uc[rtl][i];
          uc[rtl][i] = u;
        }
    }
    // pack T_{n1+1} -> hi/lo fp16 A-frags
    f16x8 afh[2], afl[2];
#pragma unroll
    for (int rtl = 0; rtl < 2; ++rtl) {
      union UU { h16x2 h2[4]; f16x8 v; } uh, ul;
#pragma unroll
      for (int ii = 0; ii < 4; ++ii) {
        float v0 = uc[rtl][2 * ii], v1 = uc[rtl][2 * ii + 1];
        h16x2 h = __builtin_amdgcn_cvt_pkrtz(v0, v1);
        uh.h2[ii] = h;
        ul.h2[ii] = __builtin_amdgcn_cvt_pkrtz(v0 - (float)h[0], v1 - (float)h[1]);
      }
      afh[rtl] = uh.v;
      afl[rtl] = ul.v;
    }
    __builtin_amdgcn_s_setprio(1);
#pragma unroll
    for (int qt = 0; qt < 4; ++qt)
#pragma unroll
      for (int rtl = 0; rtl < 2; ++rtl)
        acc[rtl][qt] = __builtin_amdgcn_mfma_f32_16x16x32_f16(afh[rtl], bh[qt],
                                                              acc[rtl][qt], 0, 0, 0);
#pragma unroll
    for (int qt = 0; qt < 4; ++qt)
#pragma unroll
      for (int rtl = 0; rtl < 2; ++rtl)
        acc[rtl][qt] = __builtin_amdgcn_mfma_f32_16x16x32_f16(afl[rtl], bh[qt],
                                                              acc[rtl][qt], 0, 0, 0);
#pragma unroll
    for (int qt = 0; qt < 4; ++qt)
#pragma unroll
      for (int rtl = 0; rtl < 2; ++rtl)
        acc[rtl][qt] = __builtin_amdgcn_mfma_f32_16x16x32_f16(afh[rtl], bl[qt],
                                                              acc[rtl][qt], 0, 0, 0);
    __builtin_amdgcn_s_setprio(0);
  }
}

// write m = 2tanh(acc) into mT; C-layout: row=rt*16+(l>>4)*4+j, col=qt*16+(l&15)
__device__ __forceinline__ void write_m(float* __restrict__ mT,
                                        const f32x4 (&acc)[2][4], int l, int wr, int wc) {
  const int c15 = l & 15, g = l >> 4;
#pragma unroll
  for (int rtl = 0; rtl < 2; ++rtl)
#pragma unroll
    for (int qt = 0; qt < 4; ++qt)
#pragma unroll
      for (int j = 0; j < 4; ++j) {
        int row = wr * 32 + rtl * 16 + g * 4 + j;
        int col = wc * 64 + qt * 16 + c15;
        mT[row * MST + col] = fast_tanh2(acc[rtl][qt][j]);
      }
}

// ---------- main kernel ----------
__global__ void __launch_bounds__(TPB, 3)
kan_mfma(const float* __restrict__ x, const float* __restrict__ Bm,
         const _Float16* __restrict__ wt_hi, const _Float16* __restrict__ wt_lo,
         const float* __restrict__ bias, const float* __restrict__ w4,
         float* __restrict__ out) {
  __shared__ float mT[64 * MST];  // 33.8 KB
  int tid = threadIdx.x;
  int l = tid & 63;
  int w = tid >> 6;
  int wr = w >> 1, wc = w & 1;
  int row0 = blockIdx.x * 64;

  // ---- Fourier features -> mT (thread: row=l, features w*8..w*8+7) ----
  {
    const float4* xp = (const float4*)(x + (size_t)(row0 + l) * 8);
    float4 a = xp[0], c4 = xp[1];
    float xv[8] = {a.x, a.y, a.z, a.w, c4.x, c4.y, c4.z, c4.w};
#pragma unroll
    for (int jj = 0; jj < 8; ++jj) {
      int j = w * 8 + jj;
      float pr = 0.0f;
#pragma unroll
      for (int k = 0; k < 8; ++k) pr = fmaf(xv[k], Bm[k * 32 + j], pr);
      float ang = 6.2831853071795864f * pr;
      float sv, cv;
      sincosf(ang, &sv, &cv);
      mT[l * MST + j] = fast_tanh2(sv);
      mT[l * MST + 32 + j] = fast_tanh2(cv);
    }
  }
  __syncthreads();

  f32x4 acc[2][4];
  layer22<2, false>(mT, wt_hi + WT_L0, wt_lo + WT_L0, bias + 0, acc, l, wr, wc);
  __syncthreads();
  write_m(mT, acc, l, wr, wc);
  __syncthreads();
  layer22<4, true>(mT, wt_hi + WT_L1, wt_lo + WT_L1, bias + 128, acc, l, wr, wc);
  __syncthreads();
  write_m(mT, acc, l, wr, wc);
  __syncthreads();
  layer22<4, true>(mT, wt_hi + WT_L2, wt_lo + WT_L2, bias + 256, acc, l, wr, wc);
  __syncthreads();
  write_m(mT, acc, l, wr, wc);
  __syncthreads();
  layer22<4, true>(mT, wt_hi + WT_L3, wt_lo + WT_L3, bias + 384, acc, l, wr, wc);
  __syncthreads();
  write_m(mT, acc, l, wr, wc);
  __syncthreads();

  // ---- L4: 128 -> 1 (wave w: rows w*16..+15; 4 lane-groups split p) ----
  {
    int r16 = l & 15, pq = l >> 4;
    int r = w * 16 + r16;
    const float* w4h = w4 + pq * 32 * 9;
    float part = 0.0f;
#pragma unroll 4
    for (int pp = 0; pp < 32; ++pp) {
      float mm = mT[r * MST + pq * 32 + pp];
      const float* wp = w4h + pp * 9;
      part += wp[0];
      part = fmaf(mm, wp[1], part);
      float u2 = 1.0f, u1 = mm;
#pragma unroll
      for (int n = 2; n < 9; ++n) {
        float u = fmaf(mm, u1, -u2);
        u2 = u1;
        u1 = u;
        part = fmaf(u, wp[n], part);
      }
    }
    part += __shfl_xor(part, 16);
    part += __shfl_xor(part, 32);
    if (l < 16) {
      float v = part;
      float t = 0.5f * fast_tanh2(v);
      float m2 = t + t;
      float tm2 = 1.0f, tm1 = t;
      float y = gelu_exact(1.0f) + gelu_exact(t);
#pragma unroll
      for (int n = 2; n <= 5; ++n) {
        float tn = fmaf(m2, tm1, -tm2);
        tm2 = tm1;
        tm1 = tn;
        y += gelu_exact(tn);
      }
      out[row0 + r] = y;
    }
  }
}

extern "C" void kernel_launch(void* const* d_in, const int* in_sizes, int n_in,
                              void* d_out, int out_size, void* d_ws, size_t ws_size,
                              hipStream_t stream) {
  const float* x   = (const float*)d_in[0];
  const float* Bm  = (const float*)d_in[1];
  const float* W0  = (const float*)d_in[2];
  const float* tW0 = (const float*)d_in[3];
  const float* W1  = (const float*)d_in[4];
  const float* tW1 = (const float*)d_in[5];
  const float* W2  = (const float*)d_in[6];
  const float* tW2 = (const float*)d_in[7];
  const float* W3  = (const float*)d_in[8];
  const float* tW3 = (const float*)d_in[9];
  const float* W4  = (const float*)d_in[10];
  const float* tW4 = (const float*)d_in[11];

  _Float16* wt_hi = (_Float16*)d_ws;
  _Float16* wt_lo = wt_hi + WT_END;
  float* fws = (float*)d_ws + F32_BASE;
  float* bias = fws;        // 4*128 floats
  float* w4 = fws + 512;    // 1152 floats

  fuse_w_f16<<<65536 / 256, 256, 0, stream>>>(W0, tW0, wt_hi + WT_L0, wt_lo + WT_L0, 64, 65536, 1);
  fuse_w_f16<<<131072 / 256, 256, 0, stream>>>(W1, tW1, wt_hi + WT_L1, wt_lo + WT_L1, 128, 131072, 2);
  fuse_w_f16<<<131072 / 256, 256, 0, stream>>>(W2, tW2, wt_hi + WT_L2, wt_lo + WT_L2, 128, 131072, 2);
  fuse_w_f16<<<131072 / 256, 256, 0, stream>>>(W3, tW3, wt_hi + WT_L3, wt_lo + WT_L3, 128, 131072, 2);
  fuse_bias<<<2, 64, 0, stream>>>(W0, tW0, bias + 0, 64, 128);
  fuse_bias<<<2, 64, 0, stream>>>(W1, tW1, bias + 128, 128, 128);
  fuse_bias<<<2, 64, 0, stream>>>(W2, tW2, bias + 256, 128, 128);
  fuse_bias<<<2, 64, 0, stream>>>(W3, tW3, bias + 384, 128, 128);
  fuse_w4<<<9, 128, 0, stream>>>(W4, tW4, w4);

  kan_mfma<<<131072 / 64, TPB, 0, stream>>>(x, Bm, wt_hi, wt_lo, bias, w4, (float*)d_out);
}